// Round 1
// baseline (14853.947 us; speedup 1.0000x reference)
//
#include <hip/hip_runtime.h>
#include <cfloat>
#include <cmath>

#define Bn 128
#define Tn 512
#define En 256
#define Hn 512
#define NTAGS 32

// ws float-offset layout (h stored transposed: [buf][k][b])
#define OFF_HF 0          // [2][512][128]
#define OFF_HB 131072     // [2][512][128]
#define OFF_CF 262144     // [512][128]
#define OFF_CB 327680     // [512][128]
#define OFF_EF 393216     // [512][32][128]  E[t][tag][b]
#define OFF_EB 2490368    // [512][32][128]
// total 4587520 floats = 17.5 MB

__global__ __launch_bounds__(512) void lstm_step_k(
    const float* __restrict__ X, const float* __restrict__ masks,
    const float* __restrict__ Wih_f, const float* __restrict__ Whh_f, const float* __restrict__ bias_f,
    const float* __restrict__ Wih_b, const float* __restrict__ Whh_b, const float* __restrict__ bias_b,
    const float* __restrict__ Wout, float* __restrict__ ws, int s)
{
  const int tid = threadIdx.x;
  const int blk = blockIdx.x;

  __shared__ float hT[64][132];   // staged h/x chunk, [k][b]
  __shared__ float WT[64][20];    // staged W chunk,   [k][c]
  __shared__ float gl[128][17];   // reduced gates [b][c]
  __shared__ float rs_[4][128];   // emission partials

  if (blk < 256) {
    // ---------------- GEMM + LSTM update block ----------------
    const int dir = blk >> 7;        // 0 = fwd, 1 = bwd
    const int bbk = blk & 127;
    const int t = dir ? (Tn - 1 - s) : s;
    const float* Wih  = dir ? Wih_b  : Wih_f;
    const float* Whh  = dir ? Whh_b  : Whh_f;
    const float* bias = dir ? bias_b : bias_f;
    float* hbuf = ws + (dir ? OFF_HB : OFF_HF);
    float* cbuf = ws + (dir ? OFF_CB : OFF_CF);
    const int rbuf = (s + 1) & 1;
    const int wbuf = s & 1;
    const float* hprev = hbuf + rbuf * (Hn * Bn);
    float*       hnext = hbuf + wbuf * (Hn * Bn);
    const int hidx0 = bbk * 4;       // this block owns h-indices [hidx0, hidx0+4)

    const int bg   = tid & 31;       // batch quad group
    const int b0   = bg * 4;
    const int cg   = (tid >> 5) & 3; // column quad group (of 16 local cols)
    const int c0   = cg * 4;
    const int kseg = tid >> 7;       // K split 0..3 (wave-uniform)

    float acc[4][4];
    #pragma unroll
    for (int m = 0; m < 4; ++m)
      #pragma unroll
      for (int n = 0; n < 4; ++n) acc[m][n] = 0.f;

    for (int kc = 0; kc < 12; ++kc) {
      const int kbase = kc * 64;
      // --- stage W chunk: 16 cols x 64 k ---
      if (tid < 256) {
        const int cw = tid >> 4;
        const int kq = (tid & 15) * 4;
        const int row = (cw >> 2) * Hn + hidx0 + (cw & 3); // gate*H + hidx
        float4 w4;
        if (kbase < Hn) w4 = *(const float4*)&Whh[(size_t)row * Hn + kbase + kq];
        else            w4 = *(const float4*)&Wih[(size_t)row * En + (kbase - Hn) + kq];
        WT[kq + 0][cw] = w4.x; WT[kq + 1][cw] = w4.y;
        WT[kq + 2][cw] = w4.z; WT[kq + 3][cw] = w4.w;
      }
      // --- stage h chunk (already [k][b]) or X chunk (transpose) ---
      if (kbase < Hn) {
        #pragma unroll
        for (int j = 0; j < 4; ++j) {
          const int q  = tid + j * 512;
          const int kk = q >> 5;
          const int b4 = (q & 31) * 4;
          float4 v = *(const float4*)&hprev[(size_t)(kbase + kk) * Bn + b4];
          *(float4*)&hT[kk][b4] = v;
        }
      } else {
        #pragma unroll
        for (int j = 0; j < 4; ++j) {
          const int q  = tid + j * 512;
          const int bq = q >> 4;
          const int kq = (q & 15) * 4;
          float4 v = *(const float4*)&X[(size_t)bq * (Tn * En) + (size_t)t * En + (kbase - Hn) + kq];
          hT[kq + 0][bq] = v.x; hT[kq + 1][bq] = v.y;
          hT[kq + 2][bq] = v.z; hT[kq + 3][bq] = v.w;
        }
      }
      __syncthreads();
      const int ks0 = kseg * 16;
      #pragma unroll
      for (int kk = 0; kk < 16; ++kk) {
        float4 hv = *(const float4*)&hT[ks0 + kk][b0];
        float4 wv = *(const float4*)&WT[ks0 + kk][c0];
        acc[0][0] += hv.x * wv.x; acc[0][1] += hv.x * wv.y; acc[0][2] += hv.x * wv.z; acc[0][3] += hv.x * wv.w;
        acc[1][0] += hv.y * wv.x; acc[1][1] += hv.y * wv.y; acc[1][2] += hv.y * wv.z; acc[1][3] += hv.y * wv.w;
        acc[2][0] += hv.z * wv.x; acc[2][1] += hv.z * wv.y; acc[2][2] += hv.z * wv.z; acc[2][3] += hv.z * wv.w;
        acc[3][0] += hv.w * wv.x; acc[3][1] += hv.w * wv.y; acc[3][2] += hv.w * wv.z; acc[3][3] += hv.w * wv.w;
      }
      __syncthreads();
    }

    // --- reduce 4 K-segments (scratch = hT memory) ---
    float* red = &hT[0][0];
    #pragma unroll
    for (int m = 0; m < 4; ++m)
      #pragma unroll
      for (int n = 0; n < 4; ++n)
        red[kseg * 2048 + (b0 + m) * 16 + (c0 + n)] = acc[m][n];
    __syncthreads();
    #pragma unroll
    for (int j = 0; j < 4; ++j) {
      const int o = tid + j * 512;
      const float g = red[o] + red[2048 + o] + red[4096 + o] + red[6144 + o];
      gl[o >> 4][o & 15] = g;
    }
    __syncthreads();

    // --- LSTM pointwise update: b = tid&127, delta = tid>>7 ---
    {
      const int b   = tid & 127;
      const int dlt = tid >> 7;
      const int hidx = hidx0 + dlt;
      const float gi = gl[b][dlt]      + bias[hidx];
      const float gf = gl[b][4 + dlt]  + bias[Hn + hidx];
      const float gc = gl[b][8 + dlt]  + bias[2 * Hn + hidx];
      const float go = gl[b][12 + dlt] + bias[3 * Hn + hidx];
      const float iv = 1.f / (1.f + expf(-gi));
      const float fv = 1.f / (1.f + expf(-gf));
      const float gv = tanhf(gc);
      const float ov = 1.f / (1.f + expf(-go));
      const float cold = cbuf[hidx * Bn + b];
      const float cnew = fv * cold + iv * gv;
      const float hold = hprev[hidx * Bn + b];
      const float hnew = ov * tanhf(cnew);
      const float m = masks[(size_t)b * Tn + t];
      hnext[hidx * Bn + b] = (m > 0.f) ? hnew : hold;
      cbuf[hidx * Bn + b]  = (m > 0.f) ? cnew : cold;
    }
  } else {
    // ---------------- emission blocks: E[t_prev][tag][b] ----------------
    if (s == 0) return;
    const int eb  = blk - 256;
    const int dir = eb >> 5;
    const int tag = eb & 31;
    const int rbuf = (s + 1) & 1;
    const float* hsrc = ws + (dir ? OFF_HB : OFF_HF) + rbuf * (Hn * Bn);
    const int tprev = dir ? (Tn - s) : (s - 1);
    const float* wrow = Wout + (size_t)tag * (2 * Hn) + dir * Hn;
    float* Edst = ws + (dir ? OFF_EB : OFF_EF);
    const int b  = tid & 127;
    const int kh = tid >> 7;
    float a = 0.f;
    #pragma unroll 4
    for (int k = kh * 128; k < kh * 128 + 128; ++k)
      a += hsrc[k * Bn + b] * wrow[k];
    rs_[kh][b] = a;
    __syncthreads();
    if (tid < 128) {
      const float v = rs_[0][tid] + rs_[1][tid] + rs_[2][tid] + rs_[3][tid];
      Edst[(size_t)tprev * (NTAGS * Bn) + tag * Bn + tid] = v;
    }
  }
}

__global__ __launch_bounds__(512) void emis_final_k(const float* __restrict__ Wout,
                                                    float* __restrict__ ws)
{
  __shared__ float rs_[4][128];
  const int tid = threadIdx.x;
  const int dir = blockIdx.x >> 5;
  const int tag = blockIdx.x & 31;
  // final states: h_f[T-1] and h_b[0] both live in buf 1 (written at s=511)
  const float* hsrc = ws + (dir ? OFF_HB : OFF_HF) + 1 * (Hn * Bn);
  const int tprev = dir ? 0 : (Tn - 1);
  const float* wrow = Wout + (size_t)tag * (2 * Hn) + dir * Hn;
  float* Edst = ws + (dir ? OFF_EB : OFF_EF);
  const int b  = tid & 127;
  const int kh = tid >> 7;
  float a = 0.f;
  #pragma unroll 4
  for (int k = kh * 128; k < kh * 128 + 128; ++k)
    a += hsrc[k * Bn + b] * wrow[k];
  rs_[kh][b] = a;
  __syncthreads();
  if (tid < 128) {
    const float v = rs_[0][tid] + rs_[1][tid] + rs_[2][tid] + rs_[3][tid];
    Edst[(size_t)tprev * (NTAGS * Bn) + tag * Bn + tid] = v;
  }
}

__global__ __launch_bounds__(64) void viterbi_k(
    const float* __restrict__ Ef, const float* __restrict__ Eb,
    const float* __restrict__ bout, const float* __restrict__ trans,
    const float* __restrict__ masks, float* __restrict__ out)
{
  const int b = blockIdx.x;
  const int l = threadIdx.x;
  __shared__ float tr[32][32];
  __shared__ float al[32];
  __shared__ float msk[512];
  __shared__ unsigned char bp[512][32];
  __shared__ int tseq[512];

  for (int i = l; i < 1024; i += 64) tr[i >> 5][i & 31] = trans[i];
  for (int i = l; i < 512; i += 64) msk[i] = masks[(size_t)b * 512 + i];
  __syncthreads();

  const int j  = l & 31;
  const int hi = l >> 5;
  if (l < 32)
    al[j] = Ef[(size_t)j * Bn + b] + Eb[(size_t)j * Bn + b] + bout[j] + tr[30][j];
  __syncthreads();

  for (int t = 1; t < 512; ++t) {
    float pmax = -FLT_MAX; int pidx = 0;
    #pragma unroll
    for (int ii = 0; ii < 16; ++ii) {
      const int i = hi * 16 + ii;
      const float sc = al[i] + tr[i][j];
      if (sc > pmax) { pmax = sc; pidx = i; }   // strict > => first occurrence
    }
    const float omax = __shfl_down(pmax, 32);
    const int   oidx = __shfl_down(pidx, 32);
    if (l < 32) {
      if (omax > pmax) { pmax = omax; pidx = oidx; } // high half only on strict >
      bp[t][j] = (unsigned char)pidx;
      const float e = Ef[(size_t)t * (NTAGS * Bn) + j * Bn + b]
                    + Eb[(size_t)t * (NTAGS * Bn) + j * Bn + b] + bout[j];
      const float na = pmax + e;
      if (msk[t] > 0.f) al[j] = na;
    }
    __syncthreads();
  }

  float fv; int fidx;
  if (l < 32) { fv = al[l] + tr[l][31]; fidx = l; }
  else        { fv = -FLT_MAX; fidx = 1 << 30; }
  #pragma unroll
  for (int off = 16; off >= 1; off >>= 1) {
    const float v2 = __shfl_xor(fv, off);
    const int   i2 = __shfl_xor(fidx, off);
    if (v2 > fv || (v2 == fv && i2 < fidx)) { fv = v2; fidx = i2; }
  }
  if (l == 0) {
    out[b] = fv;                 // max_end_scores
    int cur = fidx;
    tseq[511] = cur;
    for (int t = 511; t >= 1; --t) {
      const int prev = (msk[t] > 0.f) ? (int)bp[t][cur] : cur;
      tseq[t - 1] = prev;
      cur = prev;
    }
  }
  __syncthreads();
  for (int t = l; t < 512; t += 64) {
    const float tv = (msk[t] > 0.f) ? (float)tseq[t] : -1.0f;
    out[Bn + (size_t)b * 512 + t] = tv;
  }
}

extern "C" void kernel_launch(void* const* d_in, const int* in_sizes, int n_in,
                              void* d_out, int out_size, void* d_ws, size_t ws_size,
                              hipStream_t stream) {
  const float* X      = (const float*)d_in[0];
  const float* masks  = (const float*)d_in[1];
  // d_in[2] length: unused (masks encode it)
  const float* Wih_f  = (const float*)d_in[3];
  const float* Whh_f  = (const float*)d_in[4];
  const float* bf     = (const float*)d_in[5];
  const float* Wih_b  = (const float*)d_in[6];
  const float* Whh_b  = (const float*)d_in[7];
  const float* bb     = (const float*)d_in[8];
  const float* Wout   = (const float*)d_in[9];
  const float* bout   = (const float*)d_in[10];
  const float* trans  = (const float*)d_in[11];
  float* ws  = (float*)d_ws;
  float* out = (float*)d_out;

  // zero h/c state region (ws is poisoned once; graph replays re-run this)
  hipMemsetAsync(d_ws, 0, (size_t)OFF_EF * sizeof(float), stream);

  for (int s = 0; s < Tn; ++s)
    lstm_step_k<<<320, 512, 0, stream>>>(X, masks, Wih_f, Whh_f, bf,
                                         Wih_b, Whh_b, bb, Wout, ws, s);
  emis_final_k<<<64, 512, 0, stream>>>(Wout, ws);
  viterbi_k<<<128, 64, 0, stream>>>(ws + OFF_EF, ws + OFF_EB, bout, trans, masks, out);
}